// Round 6
// baseline (1032.649 us; speedup 1.0000x reference)
//
#include <hip/hip_runtime.h>

#define TPB 256

// ---------------------------------------------------------------------------
// B=8, H=W=256, Cin=Cout=8, N=511 (=2H-1), crop offset 127.
// Half-spectrum (k2 in [0,256)) via Hermitian-symmetrized kernel Ke.
// All GEMM dims padded to 512/256 (zero rows via zeroed table entries).
// ---------------------------------------------------------------------------

__global__ __launch_bounds__(TPB)
void build_tables_k(float2* __restrict__ Atab, float2* __restrict__ AtabTh,
                    float2* __restrict__ Ctab, float2* __restrict__ Ct2T) {
    int idx = blockIdx.x * TPB + threadIdx.x;   // [0, 131072)
    const float w = (float)(6.28318530717958647692 / 511.0);
    {
        int k = idx >> 8, n = idx & 255;
        float2 v = make_float2(0.f, 0.f);
        if (k < 511) {
            int m = (k * n) % 511;
            float s, c; sincosf(w * (float)m, &s, &c);
            v = make_float2(c, -s);
        }
        Atab[idx] = v;                           // [k*256+n], k in [0,512)
        if (k < 256) AtabTh[n * 256 + k] = v;    // [w*256+k2]
    }
    {
        int p = idx >> 9, k1 = idx & 511;
        float2 v = make_float2(0.f, 0.f);
        if (k1 < 511) {
            int m = (k1 * (p + 127)) % 511;
            float s, c; sincosf(w * (float)m, &s, &c);
            v = make_float2(c / 511.f, s / 511.f);
        }
        Ctab[p * 512 + k1] = v;                  // [p*512+k1]
    }
    if (idx < 65536) {
        int k2 = idx >> 8, q = idx & 255;
        int m = (k2 * (q + 127)) % 511;
        float s, c; sincosf(w * (float)m, &s, &c);
        float sc = (k2 == 0 ? 1.f : 2.f) / 511.f;
        Ct2T[idx] = make_float2(c * sc, s * sc); // [k2*256+q]
    }
}

// x [b][n][w][i] -> xT [(b*8+i)][n*256+w]
__global__ __launch_bounds__(TPB)
void transpose_x_k(const float4* __restrict__ x4, float* __restrict__ xT) {
    int idx = blockIdx.x * TPB + threadIdx.x;   // 8*256*256
    if (idx >= 8 * 256 * 256) return;
    float4 v0 = x4[idx * 2];
    float4 v1 = x4[idx * 2 + 1];
    float vv[8] = {v0.x, v0.y, v0.z, v0.w, v1.x, v1.y, v1.z, v1.w};
    int b  = idx >> 16;
    int nw = idx & 65535;
    float* dst = xT + ((size_t)b << 19) + nw;
    #pragma unroll
    for (int i = 0; i < 8; i++) dst[(size_t)i * 65536] = vv[i];
}

// Hermitian-symmetrize kernel into transposed half-table planes:
//   KeR/KeI[io][k1*256+k2], k1 in [0,511), k2 in [0,256)
//   Ke(k) = 0.5*(Kc(k) + conj(Kc(-k)))
__global__ __launch_bounds__(TPB)
void ksym_k(const float* __restrict__ Kr, const float* __restrict__ Ki,
            float* __restrict__ KeR, float* __restrict__ KeI) {
    __shared__ float LR[64][65];
    __shared__ float LI[64][65];
    const int tid = threadIdx.x;
    const int pt0 = blockIdx.x * 64;            // 2044 blocks * 64 = 130816
    #pragma unroll
    for (int t = 0; t < 4; t++) {
        int idx = tid + t * 256;
        int ptl = idx >> 4, j = idx & 15;
        int pt2 = pt0 + ptl;
        int k1 = pt2 >> 8, k2 = pt2 & 255;
        int k1m = (511 - k1) % 511;
        int k2m = (511 - k2) % 511;
        size_t so = ((size_t)(k1  * 511 + k2 )) * 64 + j * 4;
        size_t mo = ((size_t)(k1m * 511 + k2m)) * 64 + j * 4;
        float4 rs = *(const float4*)(Kr + so);
        float4 rm = *(const float4*)(Kr + mo);
        float4 is = *(const float4*)(Ki + so);
        float4 im = *(const float4*)(Ki + mo);
        LR[j * 4 + 0][ptl] = 0.5f * (rs.x + rm.x);
        LR[j * 4 + 1][ptl] = 0.5f * (rs.y + rm.y);
        LR[j * 4 + 2][ptl] = 0.5f * (rs.z + rm.z);
        LR[j * 4 + 3][ptl] = 0.5f * (rs.w + rm.w);
        LI[j * 4 + 0][ptl] = 0.5f * (is.x - im.x);
        LI[j * 4 + 1][ptl] = 0.5f * (is.y - im.y);
        LI[j * 4 + 2][ptl] = 0.5f * (is.z - im.z);
        LI[j * 4 + 3][ptl] = 0.5f * (is.w - im.w);
    }
    __syncthreads();
    #pragma unroll
    for (int t = 0; t < 32; t++) {
        int idx = tid + t * 256;
        int plane = idx >> 6, ptl = idx & 63;
        if (plane < 64) KeR[(size_t)plane * 131072 + pt0 + ptl] = LR[plane][ptl];
        else KeI[(size_t)(plane - 64) * 131072 + pt0 + ptl] = LI[plane - 64][ptl];
    }
}

// ---------------------------------------------------------------------------
// Batched complex GEMM, 128x128 tile, BK=16, 256 threads, 8x8 micro-tile.
// No bounds checks: M,N multiples of 128; K multiple of 16.
// A complex. BC: B complex. DR: D = Re(.) + bias[z&7].
// Asi stores NEGATED imag (an = -ai); signs via free VOP3 neg modifiers.
// B LDS rows use +4-per-32-floats additive swizzle -> 2-way max conflicts.
// ---------------------------------------------------------------------------
#define BSWZ(c) ((c) + (((c) >> 5) << 2))

template<bool BC, bool DR>
__global__ __launch_bounds__(TPB, 2)
void cgemm_k(int K,
             const float2* __restrict__ A2, int sAm, int sAb,
             const float2* __restrict__ B2, int sBk, int sBb,
             float* __restrict__ Dv, int sDm, int sDn, int sDzHi, int sDzLo,
             const float* __restrict__ bias)
{
    __shared__ float Asr[16][132];
    __shared__ float Asi[16][132];
    __shared__ float Bsr[16][140];
    __shared__ float Bsi[16][140];

    const int tid = threadIdx.x;
    const int tx = tid & 15, ty = tid >> 4;     // 16x16 thread grid
    const int bm = blockIdx.y * 128, bn = blockIdx.x * 128;
    const int z = blockIdx.z;

    const float2* A = A2 + (size_t)z * sAb;
    const float2* B = B2 + (size_t)z * sBb;

    // A staging: thread loads 4x float4 (2 cplx along k), rows mrow+32t
    const int kq   = (tid & 7) * 2;             // k-pair base
    const int mrow = tid >> 3;                  // [0,32)
    // B staging (complex): cols cc,cc+1; rows kb+4t
    const int cc = (tid & 63) * 2;
    const int kb = tid >> 6;                    // [0,4)
    // B staging (real): cols c4..c4+3; rows kbr+8t
    const int c4  = (tid & 31) * 4;
    const int kbr = tid >> 5;                   // [0,8)

    const float2* aP[4];
    #pragma unroll
    for (int t = 0; t < 4; t++)
        aP[t] = A + (size_t)(bm + mrow + 32 * t) * sAm + kq;
    const float2* bP[4];
    const float*  bPf[2];
    if constexpr (BC) {
        #pragma unroll
        for (int t = 0; t < 4; t++)
            bP[t] = B + (size_t)(kb + 4 * t) * sBk + bn + cc;
    } else {
        #pragma unroll
        for (int t = 0; t < 2; t++)
            bPf[t] = (const float*)B + (size_t)(kbr + 8 * t) * sBk + bn + c4;
    }

    float accR[8][8] = {{0.f}}, accI[8][8] = {{0.f}};
    const int m0 = ty * 8;
    const int n0s = BSWZ(tx * 8);

    for (int k0 = 0; k0 < K; k0 += 16) {
        // ---- stage A (128m x 16k cplx) ----
        #pragma unroll
        for (int t = 0; t < 4; t++) {
            float4 v = *(const float4*)aP[t];  aP[t] += 16;
            int m = mrow + 32 * t;
            Asr[kq][m]     = v.x;  Asi[kq][m]     = -v.y;
            Asr[kq + 1][m] = v.z;  Asi[kq + 1][m] = -v.w;
        }
        // ---- stage B (16k x 128n) ----
        if constexpr (BC) {
            #pragma unroll
            for (int t = 0; t < 4; t++) {
                float4 v = *(const float4*)bP[t];
                bP[t] += (size_t)16 * sBk;              // FIX: advance full BK=16
                int r = kb + 4 * t, cs = BSWZ(cc);
                *(float2*)&Bsr[r][cs] = make_float2(v.x, v.z);
                *(float2*)&Bsi[r][cs] = make_float2(v.y, v.w);
            }
        } else {
            #pragma unroll
            for (int t = 0; t < 2; t++) {
                float4 v = *(const float4*)bPf[t];
                bPf[t] += (size_t)16 * sBk;             // FIX: advance full BK=16
                int r = kbr + 8 * t, cs = BSWZ(c4);
                *(float4*)&Bsr[r][cs] = v;
            }
        }
        __syncthreads();

        #pragma unroll 4
        for (int kk = 0; kk < 16; kk++) {
            float ar[8], an[8], br[8], bi[8];
            *(float4*)&ar[0] = *(const float4*)&Asr[kk][m0];
            *(float4*)&ar[4] = *(const float4*)&Asr[kk][m0 + 4];
            *(float4*)&an[0] = *(const float4*)&Asi[kk][m0];
            *(float4*)&an[4] = *(const float4*)&Asi[kk][m0 + 4];
            *(float4*)&br[0] = *(const float4*)&Bsr[kk][n0s];
            *(float4*)&br[4] = *(const float4*)&Bsr[kk][n0s + 4];
            if constexpr (BC) {
                *(float4*)&bi[0] = *(const float4*)&Bsi[kk][n0s];
                *(float4*)&bi[4] = *(const float4*)&Bsi[kk][n0s + 4];
            }
            #pragma unroll
            for (int i = 0; i < 8; i++)
                #pragma unroll
                for (int j = 0; j < 8; j++) {
                    if constexpr (BC && !DR) {
                        accR[i][j] = fmaf(ar[i], br[j], accR[i][j]);
                        accR[i][j] = fmaf(an[i], bi[j], accR[i][j]);
                        accI[i][j] = fmaf(ar[i], bi[j], accI[i][j]);
                        accI[i][j] = fmaf(-an[i], br[j], accI[i][j]);
                    } else if constexpr (BC && DR) {
                        accR[i][j] = fmaf(ar[i], br[j], accR[i][j]);
                        accR[i][j] = fmaf(an[i], bi[j], accR[i][j]);
                    } else {
                        accR[i][j] = fmaf(ar[i], br[j], accR[i][j]);
                        accI[i][j] = fmaf(-an[i], br[j], accI[i][j]);
                    }
                }
        }
        __syncthreads();
    }

    float bz = 0.f;
    if constexpr (DR) { if (bias != nullptr) bz = bias[z & 7]; }

    const size_t dbase = (size_t)(z >> 3) * sDzHi + (size_t)(z & 7) * sDzLo;
    #pragma unroll
    for (int i = 0; i < 8; i++) {
        int gm = bm + m0 + i;
        if constexpr (DR) {
            #pragma unroll
            for (int j = 0; j < 8; j++) {
                int gn = bn + tx * 8 + j;
                Dv[dbase + (size_t)gm * sDm + (size_t)gn * sDn] = accR[i][j] + bz;
            }
        } else {
            // complex, sDn==1: 8 consecutive float2 -> 4x float4 stores
            size_t off = dbase + (size_t)gm * sDm + bn + tx * 8;
            float4* drow = (float4*)((float2*)Dv + off);
            #pragma unroll
            for (int j = 0; j < 4; j++)
                drow[j] = make_float4(accR[i][2 * j], accI[i][2 * j],
                                      accR[i][2 * j + 1], accI[i][2 * j + 1]);
        }
    }
}

// ---------------------------------------------------------------------------
// In-place channel mix on half-spectrum, one (pt, image) per thread:
//   F2[m*8+o][pt] = sum_i F2[m*8+i][pt] * Ke[i*8+o][pt]
// ---------------------------------------------------------------------------
__global__ __launch_bounds__(TPB)
void einsum_k(float2* __restrict__ F2, const float* __restrict__ KeR,
              const float* __restrict__ KeI)
{
    int pt = blockIdx.x * TPB + threadIdx.x;    // [0, 131072)
    float2* F = F2 + (size_t)blockIdx.y * (8 * 131072);

    float xr[8], xi[8];
    #pragma unroll
    for (int i = 0; i < 8; i++) {
        float2 v = F[(size_t)i * 131072 + pt];
        xr[i] = v.x; xi[i] = v.y;
    }
    float ar[8] = {0.f}, ai[8] = {0.f};
    #pragma unroll
    for (int i = 0; i < 8; i++) {
        #pragma unroll
        for (int o = 0; o < 8; o++) {
            float kr = KeR[(size_t)(i * 8 + o) * 131072 + pt];
            float ki = KeI[(size_t)(i * 8 + o) * 131072 + pt];
            ar[o] = fmaf(xr[i], kr, ar[o]);
            ar[o] = fmaf(-xi[i], ki, ar[o]);
            ai[o] = fmaf(xr[i], ki, ai[o]);
            ai[o] = fmaf(xi[i], kr, ai[o]);
        }
    }
    #pragma unroll
    for (int o = 0; o < 8; o++)
        F[(size_t)o * 131072 + pt] = make_float2(ar[o], ai[o]);
}

// ---------------------------------------------------------------------------

extern "C" void kernel_launch(void* const* d_in, const int* in_sizes, int n_in,
                              void* d_out, int out_size, void* d_ws, size_t ws_size,
                              hipStream_t stream) {
    const float* x    = (const float*)d_in[0];
    const float* Kr   = (const float*)d_in[1];
    const float* Ki   = Kr + 16711744;          // 511*511*64
    const float* bias = (const float*)d_in[2];
    float* out = (float*)d_out;
    char* ws = (char*)d_ws;

    float2* Atab   = (float2*)(ws + 0);          //  1,048,576
    float2* AtabTh = (float2*)(ws + 1048576);    //    524,288
    float2* Ctab   = (float2*)(ws + 1572864);    //  1,048,576
    float2* Ct2T   = (float2*)(ws + 2621440);    //    524,288
    float*  xT     = (float*) (ws + 3145728);    // 16,777,216
    float*  KeR    = (float*) (ws + 19922944);   // 33,554,432
    float*  KeI    = (float*) (ws + 53477376);   // 33,554,432
    const size_t fixedEnd = 87031808;

    int g = 1;
    for (int cand = 8; cand >= 1; cand >>= 1) {
        if (fixedEnd + (size_t)cand * 16777216 <= ws_size) { g = cand; break; }
    }
    float2* F1 = (float2*)(ws + fixedEnd);                        // g*8,388,608
    float2* F2 = (float2*)(ws + fixedEnd + (size_t)g * 8388608);  // g*8,388,608

    build_tables_k<<<512, TPB, 0, stream>>>(Atab, AtabTh, Ctab, Ct2T);
    transpose_x_k<<<2048, TPB, 0, stream>>>((const float4*)x, xT);
    ksym_k<<<2044, TPB, 0, stream>>>(Kr, Ki, KeR, KeI);

    for (int b0 = 0; b0 < 8; b0 += g) {
        int Z = g * 8;
        // S1: F1[z][k1*256+w] = sum_n Atab[k1,n]*x[z][n][w]   (B real)
        cgemm_k<false, false><<<dim3(2, 4, Z), TPB, 0, stream>>>(
            256, Atab, 256, 0,
            (const float2*)xT + (size_t)b0 * 8 * 32768, 256, 32768,
            (float*)F1, 256, 1, 1048576, 131072, nullptr);

        // S2: F2[z][k1*256+k2] = sum_w F1[z][k1*256+w]*AtabTh[w*256+k2]
        cgemm_k<true, false><<<dim3(2, 4, Z), TPB, 0, stream>>>(
            256, F1, 256, 131072,
            AtabTh, 256, 0,
            (float*)F2, 256, 1, 1048576, 131072, nullptr);

        // S3: in-place channel mix
        einsum_k<<<dim3(512, g), TPB, 0, stream>>>(F2, KeR, KeI);

        // S4: F1[z][p*256+k2] = sum_k1 Ctab[p*512+k1]*F2[z][k1*256+k2]
        cgemm_k<true, false><<<dim3(2, 2, Z), TPB, 0, stream>>>(
            512, Ctab, 512, 0,
            F2, 256, 131072,
            (float*)F1, 256, 1, 1048576, 131072, nullptr);

        // S5: out[m][p][q][o] = Re(sum_k2 F1[z][p*256+k2]*Ct2T[k2*256+q]) + bias[o]
        cgemm_k<true, true><<<dim3(2, 2, Z), TPB, 0, stream>>>(
            256, F1, 256, 131072,
            Ct2T, 256, 0,
            out + (size_t)b0 * 524288, 2048, 8, 524288, 1, bias);
    }
}